// Round 2
// baseline (457.125 us; speedup 1.0000x reference)
//
#include <hip/hip_runtime.h>

#define FLT_MAX_ 3.402823466e+38f

constexpr int PARTS = 8;        // waves per workgroup (K-dim parts)
constexpr int CB    = 4;        // channels per part (32/8)
constexpr int HW    = 9216;     // 96*96
constexpr int XT    = 32 * 4 * 34;   // x tile: [ch 32][row 4][col 34] = 4352 floats

__global__ __launch_bounds__(512, 6)   // cap ~85 VGPR -> 3 WGs/CU (LDS 50.8KB)
void sac_fused(const float* __restrict__ x,
               const float* __restrict__ fc1_w, const float* __restrict__ fc1_b,
               const float* __restrict__ alpha_w, const float* __restrict__ alpha_b,
               const float* __restrict__ phi_w, const float* __restrict__ phi_b,
               const float* __restrict__ bn_g, const float* __restrict__ bn_b,
               const float* __restrict__ bn_m, const float* __restrict__ bn_v,
               float* __restrict__ out)
{
    __shared__ float    xtile[XT];          // 17408 B
    __shared__ float    h_lds[64 * 66];     // 16896 B  [pos][k] pad 66 (2-way=free, b64-able)
    __shared__ float    redA[3 * 512];      // 6144 B: pass1 {S,Mn,Mx}; [0..511] reused as redP
    __shared__ float    redB[3 * 512];      // 6144 B: pass2 {S2,S3,S4}
    __shared__ unsigned cnts[16 * 64];      // 4096 B  [bin][pos]
    __shared__ float    stats_lds[64 * 5];  // 1280 B  [pos][mu,sig,gam,kap,ent]

    const int tid  = threadIdx.x;
    const int lane = tid & 63;
    const int w    = __builtin_amdgcn_readfirstlane(tid >> 6);   // wave-uniform part id
    const int g    = blockIdx.x;
    const int b    = g / 144;
    const int rem  = g - b * 144;
    const int ty   = rem / 3;               // 0..47  (row pair)
    const int tx   = rem - ty * 3;          // 0..2   (32-col third)
    const int y0   = ty * 2, x0 = tx * 32;
    const int r    = lane >> 5;             // row within tile (0..1)
    const int c    = lane & 31;             // col within tile (0..31)
    const int row  = y0 + r, col = x0 + c;

    // zero histogram
    cnts[tid] = 0u;
    cnts[tid + 512] = 0u;

    // ---------------- stage x tile (with halo, zero-padded) ----------------
    const float* __restrict__ xb = x + (size_t)b * 32 * HW;
    #pragma unroll
    for (int i = 0; i < 9; ++i) {
        const int idx = tid + i * 512;
        if (idx < XT) {
            const int ch   = idx / 136;             // const-divisor magic mul
            const int rem2 = idx - ch * 136;
            const int rr   = rem2 / 34;
            const int cc2  = rem2 - rr * 34;
            const int yg   = y0 + rr - 1;
            const int xg   = x0 + cc2 - 1;
            float v = 0.f;
            if ((unsigned)yg < 96u && (unsigned)xg < 96u)
                v = xb[ch * HW + yg * 96 + xg];
            xtile[idx] = v;
        }
    }
    __syncthreads();                                 // B0: xtile + cnts ready

    const int xoff = (w * CB) * 136 + r * 34 + c;    // per-lane vaddr; taps are imm offsets

    // ---------------- pass 1: sum / min / max (36 taps from LDS) ----------------
    float sum = 0.f, mn = FLT_MAX_, mx = -FLT_MAX_;
    #pragma unroll
    for (int cc = 0; cc < CB; ++cc)
        #pragma unroll
        for (int dy = 0; dy < 3; ++dy)
            #pragma unroll
            for (int dx = 0; dx < 3; ++dx) {
                const float p = xtile[xoff + cc * 136 + dy * 34 + dx];
                sum += p;
                mn = fminf(mn, p);
                mx = fmaxf(mx, p);
            }
    redA[tid] = sum; redA[512 + tid] = mn; redA[1024 + tid] = mx;
    __syncthreads();                                 // B1

    float tsum = 0.f, tmn = FLT_MAX_, tmx = -FLT_MAX_;
    #pragma unroll
    for (int rr = 0; rr < PARTS; ++rr) {
        tsum += redA[rr * 64 + lane];
        tmn = fminf(tmn, redA[512 + rr * 64 + lane]);
        tmx = fmaxf(tmx, redA[1024 + rr * 64 + lane]);
    }
    const float mu  = tsum / 288.0f;
    const float rng = (tmx - tmn) + 1e-6f;           // IEEE, matches ref

    // ---------------- pass 2: central moments + histogram + phi_b.p ----------------
    float s2 = 0.f, s3 = 0.f, s4 = 0.f, projp = 0.f;
    #pragma unroll
    for (int cc = 0; cc < CB; ++cc)
        #pragma unroll
        for (int dy = 0; dy < 3; ++dy)
            #pragma unroll
            for (int dx = 0; dx < 3; ++dx) {
                const float p  = xtile[xoff + cc * 136 + dy * 34 + dx];
                const float d  = p - mu;
                const float d2 = d * d;
                s2 += d2; s3 += d2 * d; s4 += d2 * d2;
                const int j = (w * CB + cc) * 9 + dy * 3 + dx;       // uniform
                projp = fmaf(p, phi_b[j], projp);                    // s_load
                // IEEE division: bin decision bit-matches reference
                const float pn = (p - tmn) / rng;
                int bi = (int)(pn * 15.0f);
                bi = bi < 0 ? 0 : (bi > 15 ? 15 : bi);
                atomicAdd(&cnts[bi * 64 + lane], 1u);
            }
    redB[tid] = s2; redB[512 + tid] = s3; redB[1024 + tid] = s4;
    __syncthreads();                                 // B2

    // ---------------- finalize stats (wave 0; lane = position) ----------------
    if (w == 0) {
        float u2 = 0.f, u3 = 0.f, u4 = 0.f;
        #pragma unroll
        for (int rr = 0; rr < PARTS; ++rr) {
            u2 += redB[rr * 64 + lane];
            u3 += redB[512 + rr * 64 + lane];
            u4 += redB[1024 + rr * 64 + lane];
        }
        const float var  = u2 / 288.0f;
        const float sig  = sqrtf(var + 1e-6f);
        const float inv  = 1.0f / (sig + 1e-6f);
        const float inv2 = inv * inv;
        const float gam  = (u3 * (inv2 * inv)) / 288.0f;
        const float kap  = (u4 * (inv2 * inv2)) / 288.0f - 3.0f;
        float ent = 0.f;
        #pragma unroll
        for (int bi = 0; bi < 16; ++bi) {
            const float prob = (float)cnts[bi * 64 + lane] * (1.0f / 288.0f);
            ent -= prob * __logf(prob + 1e-9f);
        }
        stats_lds[lane * 5 + 0] = mu;
        stats_lds[lane * 5 + 1] = sig;
        stats_lds[lane * 5 + 2] = gam;
        stats_lds[lane * 5 + 3] = kap;
        stats_lds[lane * 5 + 4] = ent;
    }
    __syncthreads();                                 // B3

    // ---------------- h = relu(stats @ fc1_w^T + fc1_b) -> LDS ----------------
    #pragma unroll
    for (int it = 0; it < 8; ++it) {
        const int idx = tid + it * 512;
        const int pp  = idx >> 6;                    // wave-uniform position
        const int k   = idx & 63;
        float acc = fc1_b[k];
        #pragma unroll
        for (int s5 = 0; s5 < 5; ++s5)
            acc += stats_lds[pp * 5 + s5] * fc1_w[k * 5 + s5];
        h_lds[pp * 66 + k] = fmaxf(acc, 0.f);
    }
    __syncthreads();                                 // B4

    // ---------------- t[k] = sum_j p[j]*phi_w[j,k], two 32-wide halves ----------------
    #pragma unroll 1   // do NOT unroll: keeps live accumulators at 32
    for (int half = 0; half < 2; ++half) {
        float t32[32];
        #pragma unroll
        for (int k = 0; k < 32; ++k) t32[k] = 0.f;
        #pragma unroll
        for (int cc = 0; cc < CB; ++cc)
            #pragma unroll
            for (int dy = 0; dy < 3; ++dy)
                #pragma unroll
                for (int dx = 0; dx < 3; ++dx) {
                    const int j   = (w * CB + cc) * 9 + dy * 3 + dx;  // uniform
                    const float p = xtile[xoff + cc * 136 + dy * 34 + dx];
                    const float* __restrict__ pw = phi_w + j * 64 + half * 32; // s_load
                    #pragma unroll
                    for (int k = 0; k < 32; ++k)
                        t32[k] = fmaf(p, pw[k], t32[k]);
                }
        #pragma unroll
        for (int k = 0; k < 32; ++k)
            projp += h_lds[lane * 66 + half * 32 + k] * t32[k];
    }
    redA[tid] = projp;                               // alias over pass1-S (dead since B2)
    __syncthreads();                                 // B5
    float proj = 0.f;
    #pragma unroll
    for (int rr = 0; rr < PARTS; ++rr) proj += redA[rr * 64 + lane];

    // ---------------- alpha (8 channels per part) + BN + SiLU ----------------
    float acc8[8];
    #pragma unroll
    for (int cj = 0; cj < 8; ++cj) acc8[cj] = 0.f;
    #pragma unroll 16
    for (int k = 0; k < 64; ++k) {
        const float hk = h_lds[lane * 66 + k];
        #pragma unroll
        for (int cj = 0; cj < 8; ++cj)
            acc8[cj] = fmaf(hk, alpha_w[(w * 8 + cj) * 64 + k], acc8[cj]); // s_load
    }
    #pragma unroll
    for (int cj = 0; cj < 8; ++cj) {
        const int ch     = w * 8 + cj;
        const float a    = acc8[cj] + alpha_b[ch];
        const float o    = a * proj;
        const float binv = bn_g[ch] * rsqrtf(bn_v[ch] + 1e-5f);
        const float yv   = (o - bn_m[ch]) * binv + bn_b[ch];
        const float sv   = __fdividef(yv, 1.0f + __expf(-yv));   // silu
        out[((size_t)(b * 64 + ch)) * HW + (size_t)(row * 96 + col)] = sv;
    }
}

extern "C" void kernel_launch(void* const* d_in, const int* in_sizes, int n_in,
                              void* d_out, int out_size, void* d_ws, size_t ws_size,
                              hipStream_t stream) {
    const float* x   = (const float*)d_in[0];
    const float* f1w = (const float*)d_in[1];
    const float* f1b = (const float*)d_in[2];
    const float* aw  = (const float*)d_in[3];
    const float* ab  = (const float*)d_in[4];
    const float* pw  = (const float*)d_in[5];
    const float* pb  = (const float*)d_in[6];
    const float* bg  = (const float*)d_in[7];
    const float* bb  = (const float*)d_in[8];
    const float* bm  = (const float*)d_in[9];
    const float* bv  = (const float*)d_in[10];

    sac_fused<<<dim3(576), dim3(512), 0, stream>>>(
        x, f1w, f1b, aw, ab, pw, pb, bg, bb, bm, bv, (float*)d_out);
}

// Round 3
// 47.632 us; speedup vs baseline: 9.5969x; 9.5969x over previous
//
#include <hip/hip_runtime.h>

#define FLT_MAX_ 3.402823466e+38f

constexpr int PARTS = 8;             // waves per workgroup (K-dim parts)
constexpr int CB    = 4;             // channels per part (32/8)
constexpr int HW    = 9216;          // 96*96
constexpr int XT    = 32 * 4 * 34;   // x tile: [ch 32][row 4][col 34] = 4352 floats

__global__ __launch_bounds__(512, 3)  // observed semantics: 3 blocks/CU -> ~85 VGPR budget
void sac_fused(const float* __restrict__ x,
               const float* __restrict__ fc1_w, const float* __restrict__ fc1_b,
               const float* __restrict__ alpha_w, const float* __restrict__ alpha_b,
               const float* __restrict__ phi_w, const float* __restrict__ phi_b,
               const float* __restrict__ bn_g, const float* __restrict__ bn_b,
               const float* __restrict__ bn_m, const float* __restrict__ bn_v,
               float* __restrict__ out)
{
    __shared__ float    xtile[XT];          // 17408 B
    __shared__ float    h_lds[64 * 65];     // 16640 B  [pos][k] pad 65: (lane+k)%32 conflict-free
    __shared__ float    red6[6 * 512];      // 12288 B  {s1,mn,mx,s2,s3,s4}; [0..511] reused as redP
    __shared__ unsigned cnts[16 * 64];      //  4096 B  [bin][pos] -> bank lane%32, 2-way free
    __shared__ float    stats_lds[64 * 5];  //  1280 B  [pos][mu,sig,gam,kap,ent]
                                            // total 51712 B -> 3 WGs/CU by LDS

    const int tid  = threadIdx.x;
    const int lane = tid & 63;
    const int w    = __builtin_amdgcn_readfirstlane(tid >> 6);   // wave-uniform part id
    const int g    = blockIdx.x;
    const int b    = g / 144;
    const int rem  = g - b * 144;
    const int ty   = rem / 3;               // 0..47  (row pair)
    const int tx   = rem - ty * 3;          // 0..2   (32-col third)
    const int y0   = ty * 2, x0 = tx * 32;
    const int r    = lane >> 5;             // row within pair (0..1)
    const int c    = lane & 31;             // col within third (0..31)
    const int row  = y0 + r, col = x0 + c;

    // zero histogram
    cnts[tid] = 0u;
    cnts[tid + 512] = 0u;

    // ---------------- stage x tile (with halo, zero-padded) ----------------
    const float* __restrict__ xb = x + (size_t)b * 32 * HW;
    #pragma unroll
    for (int i = 0; i < 9; ++i) {
        const int idx = tid + i * 512;
        if (idx < XT) {
            const int ch   = idx / 136;
            const int rem2 = idx - ch * 136;
            const int rr   = rem2 / 34;
            const int cc2  = rem2 - rr * 34;
            const int yg   = y0 + rr - 1;
            const int xg   = x0 + cc2 - 1;
            float v = 0.f;
            if ((unsigned)yg < 96u && (unsigned)xg < 96u)
                v = xb[ch * HW + yg * 96 + xg];
            xtile[idx] = v;
        }
    }
    __syncthreads();                                 // B0: xtile + cnts ready

    const int xoff = (w * CB) * 136 + r * 34 + c;    // per-lane vaddr; taps are imm offsets

    // ------------- pass A: power sums s1..s4, min, max, phi_b.p (one tap pass) -------------
    float s1 = 0.f, s2 = 0.f, s3 = 0.f, s4 = 0.f;
    float mn = FLT_MAX_, mx = -FLT_MAX_, projp = 0.f;
    #pragma unroll
    for (int cc = 0; cc < CB; ++cc)
        #pragma unroll
        for (int dy = 0; dy < 3; ++dy)
            #pragma unroll
            for (int dx = 0; dx < 3; ++dx) {
                const float p  = xtile[xoff + cc * 136 + dy * 34 + dx];
                const float pp = p * p;
                s1 += p;
                s2 = fmaf(p, p, s2);
                s3 = fmaf(pp, p, s3);
                s4 = fmaf(pp, pp, s4);
                mn = fminf(mn, p);
                mx = fmaxf(mx, p);
                const int j = (w * CB + cc) * 9 + dy * 3 + dx;   // uniform -> s_load
                projp = fmaf(p, phi_b[j], projp);
            }
    red6[tid]            = s1;
    red6[512 + tid]      = mn;
    red6[1024 + tid]     = mx;
    red6[1536 + tid]     = s2;
    red6[2048 + tid]     = s3;
    red6[2560 + tid]     = s4;
    __syncthreads();                                 // B1

    float ts1 = 0.f, tmn = FLT_MAX_, tmx = -FLT_MAX_;
    #pragma unroll
    for (int rr = 0; rr < PARTS; ++rr) {
        ts1 += red6[rr * 64 + lane];
        tmn = fminf(tmn, red6[512 + rr * 64 + lane]);
        tmx = fmaxf(tmx, red6[1024 + rr * 64 + lane]);
    }
    const float mu   = ts1 * (1.0f / 288.0f);
    const float rng  = (tmx - tmn) + 1e-6f;          // exact: min/max order-free
    const float invr = 1.0f / rng;                   // one IEEE div per position

    // ---------------- pass B: histogram only ----------------
    #pragma unroll
    for (int cc = 0; cc < CB; ++cc)
        #pragma unroll
        for (int dy = 0; dy < 3; ++dy)
            #pragma unroll
            for (int dx = 0; dx < 3; ++dx) {
                const float p  = xtile[xoff + cc * 136 + dy * 34 + dx];
                const float pn = (p - tmn) * invr;
                int bi = (int)(pn * 15.0f);
                bi = bi < 0 ? 0 : (bi > 15 ? 15 : bi);
                atomicAdd(&cnts[bi * 64 + lane], 1u);
            }
    __syncthreads();                                 // B2: cnts final

    // ---------------- finalize stats (wave 0; lane = position) ----------------
    if (w == 0) {
        float u2 = 0.f, u3 = 0.f, u4 = 0.f;
        #pragma unroll
        for (int rr = 0; rr < PARTS; ++rr) {
            u2 += red6[1536 + rr * 64 + lane];
            u3 += red6[2048 + rr * 64 + lane];
            u4 += red6[2560 + rr * 64 + lane];
        }
        const float e2 = u2 * (1.0f / 288.0f);       // E[p^2]
        const float e3 = u3 * (1.0f / 288.0f);
        const float e4 = u4 * (1.0f / 288.0f);
        const float mu2 = mu * mu;
        const float var = fmaxf(e2 - mu2, 0.f);
        const float m3  = e3 - 3.f * mu * e2 + 2.f * mu * mu2;
        const float m4  = e4 - 4.f * mu * e3 + 6.f * mu2 * e2 - 3.f * mu2 * mu2;
        const float sig = sqrtf(var + 1e-6f);
        const float inv = 1.0f / (sig + 1e-6f);
        const float inv2 = inv * inv;
        const float gam = m3 * (inv2 * inv);
        const float kap = m4 * (inv2 * inv2) - 3.0f;
        float ent = 0.f;
        #pragma unroll
        for (int bi = 0; bi < 16; ++bi) {
            const float prob = (float)cnts[bi * 64 + lane] * (1.0f / 288.0f);
            ent -= prob * __logf(prob + 1e-9f);
        }
        stats_lds[lane * 5 + 0] = mu;
        stats_lds[lane * 5 + 1] = sig;
        stats_lds[lane * 5 + 2] = gam;
        stats_lds[lane * 5 + 3] = kap;
        stats_lds[lane * 5 + 4] = ent;
    }
    __syncthreads();                                 // B3

    // ---------------- h = relu(stats @ fc1_w^T + fc1_b) -> LDS ----------------
    {
        // k = tid&63 is fixed per thread -> hoist its fc1 row
        const int k = lane;
        float wk0 = fc1_w[k * 5 + 0], wk1 = fc1_w[k * 5 + 1], wk2 = fc1_w[k * 5 + 2];
        float wk3 = fc1_w[k * 5 + 3], wk4 = fc1_w[k * 5 + 4];
        float bk  = fc1_b[k];
        #pragma unroll
        for (int it = 0; it < 8; ++it) {
            const int pp = (tid + it * 512) >> 6;    // wave-uniform position
            float acc = bk;
            acc = fmaf(stats_lds[pp * 5 + 0], wk0, acc);
            acc = fmaf(stats_lds[pp * 5 + 1], wk1, acc);
            acc = fmaf(stats_lds[pp * 5 + 2], wk2, acc);
            acc = fmaf(stats_lds[pp * 5 + 3], wk3, acc);
            acc = fmaf(stats_lds[pp * 5 + 4], wk4, acc);
            h_lds[pp * 65 + k] = fmaxf(acc, 0.f);
        }
    }
    __syncthreads();                                 // B4

    // ------- t[k]=sum_j p_j phi_w[j,k] in two 32-halves; fused h.t and alpha dots -------
    float acc8[8];
    #pragma unroll
    for (int cj = 0; cj < 8; ++cj) acc8[cj] = 0.f;

    #pragma unroll 1   // one t32 alive at a time
    for (int half = 0; half < 2; ++half) {
        float t32[32];
        #pragma unroll
        for (int k = 0; k < 32; ++k) t32[k] = 0.f;
        #pragma unroll 1   // limit live tap values
        for (int cc = 0; cc < CB; ++cc) {
            #pragma unroll
            for (int dy = 0; dy < 3; ++dy)
                #pragma unroll
                for (int dx = 0; dx < 3; ++dx) {
                    const int j   = (w * CB + cc) * 9 + dy * 3 + dx;       // uniform
                    const float p = xtile[xoff + cc * 136 + dy * 34 + dx];
                    const float* __restrict__ pw = phi_w + j * 64 + half * 32; // s_load
                    #pragma unroll
                    for (int k = 0; k < 32; ++k)
                        t32[k] = fmaf(p, pw[k], t32[k]);
                }
        }
        const float* __restrict__ aw = alpha_w + (w * 8) * 64 + half * 32;
        #pragma unroll
        for (int k = 0; k < 32; ++k) {
            const float hk = h_lds[lane * 65 + half * 32 + k];
            projp = fmaf(hk, t32[k], projp);
            #pragma unroll
            for (int cj = 0; cj < 8; ++cj)
                acc8[cj] = fmaf(hk, aw[cj * 64 + k], acc8[cj]);            // s_load
        }
    }
    red6[tid] = projp;        // s1 slice dead since just after B1
    __syncthreads();                                 // B5
    float proj = 0.f;
    #pragma unroll
    for (int rr = 0; rr < PARTS; ++rr) proj += red6[rr * 64 + lane];

    // ---------------- alpha + BN + SiLU + store ----------------
    #pragma unroll
    for (int cj = 0; cj < 8; ++cj) {
        const int ch     = w * 8 + cj;
        const float a    = acc8[cj] + alpha_b[ch];
        const float o    = a * proj;
        const float binv = bn_g[ch] * rsqrtf(bn_v[ch] + 1e-5f);
        const float yv   = (o - bn_m[ch]) * binv + bn_b[ch];
        const float sv   = __fdividef(yv, 1.0f + __expf(-yv));   // silu
        out[((size_t)(b * 64 + ch)) * HW + (size_t)(row * 96 + col)] = sv;
    }
}

extern "C" void kernel_launch(void* const* d_in, const int* in_sizes, int n_in,
                              void* d_out, int out_size, void* d_ws, size_t ws_size,
                              hipStream_t stream) {
    const float* x   = (const float*)d_in[0];
    const float* f1w = (const float*)d_in[1];
    const float* f1b = (const float*)d_in[2];
    const float* aw  = (const float*)d_in[3];
    const float* ab  = (const float*)d_in[4];
    const float* pw  = (const float*)d_in[5];
    const float* pb  = (const float*)d_in[6];
    const float* bg  = (const float*)d_in[7];
    const float* bb  = (const float*)d_in[8];
    const float* bm  = (const float*)d_in[9];
    const float* bv  = (const float*)d_in[10];

    sac_fused<<<dim3(576), dim3(512), 0, stream>>>(
        x, f1w, f1b, aw, ab, pw, pb, bg, bb, bm, bv, (float*)d_out);
}

// Round 4
// 44.242 us; speedup vs baseline: 10.3323x; 1.0766x over previous
//
#include <hip/hip_runtime.h>

#define FLT_MAX_ 3.402823466e+38f

constexpr int PARTS = 8;             // waves per workgroup
constexpr int CB    = 4;             // channels per part for the STATS passes (32/8)
constexpr int HW    = 9216;          // 96*96
constexpr int XT    = 32 * 4 * 34;   // x tile: [ch 32][row 4][col 34] = 4352 floats

__global__ __launch_bounds__(512)
void sac_fused(const float* __restrict__ x,
               const float* __restrict__ fc1_w, const float* __restrict__ fc1_b,
               const float* __restrict__ alpha_w, const float* __restrict__ alpha_b,
               const float* __restrict__ phi_w, const float* __restrict__ phi_b,
               const float* __restrict__ bn_g, const float* __restrict__ bn_b,
               const float* __restrict__ bn_m, const float* __restrict__ bn_v,
               float* __restrict__ out)
{
    __shared__ float    xtile[XT];          // 17408 B
    __shared__ float    h_lds[64 * 65];     // 16640 B [pos][k] pad 65: (lane+k)%32 conflict-free
    __shared__ float    red6[6 * 512];      // 12288 B {s1,mn,mx,s2,s3,s4}; [0..511] reused as redP
    __shared__ unsigned cnts[16 * 64];      //  4096 B [bin][pos]
    __shared__ float    stats_lds[64 * 5];  //  1280 B
                                            // total 51712 B -> 3 WGs/CU by LDS

    const int tid  = threadIdx.x;
    const int lane = tid & 63;
    const int w    = __builtin_amdgcn_readfirstlane(tid >> 6);   // wave-uniform
    const int g    = blockIdx.x;
    const int b    = g / 144;
    const int rem  = g - b * 144;
    const int ty   = rem / 3;               // 0..47  (row pair)
    const int tx   = rem - ty * 3;          // 0..2   (32-col third)
    const int y0   = ty * 2, x0 = tx * 32;
    const int r    = lane >> 5;             // row within pair (0..1)
    const int c    = lane & 31;             // col within third (0..31)
    const int row  = y0 + r, col = x0 + c;

    cnts[tid] = 0u;
    cnts[tid + 512] = 0u;

    // ---------------- stage x tile (with halo, zero-padded) ----------------
    const float* __restrict__ xb = x + (size_t)b * 32 * HW;
    #pragma unroll
    for (int i = 0; i < 9; ++i) {
        const int idx = tid + i * 512;
        if (idx < XT) {
            const int ch   = idx / 136;
            const int rem2 = idx - ch * 136;
            const int rr   = rem2 / 34;
            const int cc2  = rem2 - rr * 34;
            const int yg   = y0 + rr - 1;
            const int xg   = x0 + cc2 - 1;
            float v = 0.f;
            if ((unsigned)yg < 96u && (unsigned)xg < 96u)
                v = xb[ch * HW + yg * 96 + xg];
            xtile[idx] = v;
        }
    }
    __syncthreads();                                 // B0

    const int xoff = (w * CB) * 136 + r * 34 + c;    // stats passes: channel-split

    // ------------- pass A: power sums s1..s4, min, max, phi_b.p (channel-split) -------------
    float s1 = 0.f, s2 = 0.f, s3 = 0.f, s4 = 0.f;
    float mn = FLT_MAX_, mx = -FLT_MAX_, projp = 0.f;
    #pragma unroll
    for (int cc = 0; cc < CB; ++cc)
        #pragma unroll
        for (int dy = 0; dy < 3; ++dy)
            #pragma unroll
            for (int dx = 0; dx < 3; ++dx) {
                const float p  = xtile[xoff + cc * 136 + dy * 34 + dx];
                const float pp = p * p;
                s1 += p;
                s2 = fmaf(p, p, s2);
                s3 = fmaf(pp, p, s3);
                s4 = fmaf(pp, pp, s4);
                mn = fminf(mn, p);
                mx = fmaxf(mx, p);
                const int j = (w * CB + cc) * 9 + dy * 3 + dx;   // uniform -> s_load
                projp = fmaf(p, phi_b[j], projp);
            }
    red6[tid]        = s1;
    red6[512 + tid]  = mn;
    red6[1024 + tid] = mx;
    red6[1536 + tid] = s2;
    red6[2048 + tid] = s3;
    red6[2560 + tid] = s4;
    __syncthreads();                                 // B1

    float ts1 = 0.f, tmn = FLT_MAX_, tmx = -FLT_MAX_;
    #pragma unroll
    for (int rr = 0; rr < PARTS; ++rr) {
        ts1 += red6[rr * 64 + lane];
        tmn = fminf(tmn, red6[512 + rr * 64 + lane]);
        tmx = fmaxf(tmx, red6[1024 + rr * 64 + lane]);
    }
    const float mu   = ts1 * (1.0f / 288.0f);
    const float rng  = (tmx - tmn) + 1e-6f;          // exact: min/max order-free
    const float invr = 1.0f / rng;                   // one IEEE div per position

    // ---------------- pass B: histogram only (channel-split) ----------------
    #pragma unroll
    for (int cc = 0; cc < CB; ++cc)
        #pragma unroll
        for (int dy = 0; dy < 3; ++dy)
            #pragma unroll
            for (int dx = 0; dx < 3; ++dx) {
                const float p  = xtile[xoff + cc * 136 + dy * 34 + dx];
                const float pn = (p - tmn) * invr;
                int bi = (int)(pn * 15.0f);
                bi = bi < 0 ? 0 : (bi > 15 ? 15 : bi);
                atomicAdd(&cnts[bi * 64 + lane], 1u);
            }
    __syncthreads();                                 // B2

    // ---------------- finalize stats (wave 0; lane = position) ----------------
    if (w == 0) {
        float u2 = 0.f, u3 = 0.f, u4 = 0.f;
        #pragma unroll
        for (int rr = 0; rr < PARTS; ++rr) {
            u2 += red6[1536 + rr * 64 + lane];
            u3 += red6[2048 + rr * 64 + lane];
            u4 += red6[2560 + rr * 64 + lane];
        }
        const float e2  = u2 * (1.0f / 288.0f);
        const float e3  = u3 * (1.0f / 288.0f);
        const float e4  = u4 * (1.0f / 288.0f);
        const float mu2 = mu * mu;
        const float var = fmaxf(e2 - mu2, 0.f);
        const float m3  = e3 - 3.f * mu * e2 + 2.f * mu * mu2;
        const float m4  = e4 - 4.f * mu * e3 + 6.f * mu2 * e2 - 3.f * mu2 * mu2;
        const float sig = sqrtf(var + 1e-6f);
        const float inv = 1.0f / (sig + 1e-6f);
        const float inv2 = inv * inv;
        const float gam = m3 * (inv2 * inv);
        const float kap = m4 * (inv2 * inv2) - 3.0f;
        float ent = 0.f;
        #pragma unroll
        for (int bi = 0; bi < 16; ++bi) {
            const float prob = (float)cnts[bi * 64 + lane] * (1.0f / 288.0f);
            ent -= prob * __logf(prob + 1e-9f);
        }
        stats_lds[lane * 5 + 0] = mu;
        stats_lds[lane * 5 + 1] = sig;
        stats_lds[lane * 5 + 2] = gam;
        stats_lds[lane * 5 + 3] = kap;
        stats_lds[lane * 5 + 4] = ent;
    }
    __syncthreads();                                 // B3

    // ---------------- h = relu(stats @ fc1_w^T + fc1_b) -> LDS ----------------
    {
        const int k = lane;
        const float wk0 = fc1_w[k * 5 + 0], wk1 = fc1_w[k * 5 + 1], wk2 = fc1_w[k * 5 + 2];
        const float wk3 = fc1_w[k * 5 + 3], wk4 = fc1_w[k * 5 + 4];
        const float bk  = fc1_b[k];
        #pragma unroll
        for (int it = 0; it < 8; ++it) {
            const int pp = (tid + it * 512) >> 6;    // wave-uniform position
            float acc = bk;
            acc = fmaf(stats_lds[pp * 5 + 0], wk0, acc);
            acc = fmaf(stats_lds[pp * 5 + 1], wk1, acc);
            acc = fmaf(stats_lds[pp * 5 + 2], wk2, acc);
            acc = fmaf(stats_lds[pp * 5 + 3], wk3, acc);
            acc = fmaf(stats_lds[pp * 5 + 4], wk4, acc);
            h_lds[pp * 65 + k] = fmaxf(acc, 0.f);
        }
    }
    __syncthreads();                                 // B4

    // -------- t-loop, K-SPLIT across waves: wave w owns k = w*8 .. w*8+7 --------
    // t8[8] per lane -> register-resident, no AGPR shuffling; 2 s_load_dwordx4/tap.
    {
        float t8[8];
        #pragma unroll
        for (int kk = 0; kk < 8; ++kk) t8[kk] = 0.f;

        const int   xbase = r * 34 + c;
        const float* __restrict__ pwb = phi_w + w * 8;     // wave-uniform column base

        #pragma unroll 1   // body: 9 taps x 8 FMA; keeps I-size and SGPR pressure sane
        for (int ch2 = 0; ch2 < 32; ++ch2) {
            const float* __restrict__ pwrow = pwb + ch2 * 9 * 64;
            #pragma unroll
            for (int dy = 0; dy < 3; ++dy)
                #pragma unroll
                for (int dx = 0; dx < 3; ++dx) {
                    const float p = xtile[ch2 * 136 + xbase + dy * 34 + dx];
                    const float* __restrict__ pw = pwrow + (dy * 3 + dx) * 64; // uniform
                    #pragma unroll
                    for (int kk = 0; kk < 8; ++kk)
                        t8[kk] = fmaf(p, pw[kk], t8[kk]);
                }
        }
        #pragma unroll
        for (int kk = 0; kk < 8; ++kk)
            projp = fmaf(h_lds[lane * 65 + w * 8 + kk], t8[kk], projp);
    }
    red6[tid] = projp;        // s1 slice dead (all waves past B2>B1)
    __syncthreads();                                 // B5
    float proj = 0.f;
    #pragma unroll
    for (int rr = 0; rr < PARTS; ++rr) proj += red6[rr * 64 + lane];

    // ---------------- alpha (8 channels per wave) + BN + SiLU ----------------
    float acc8[8];
    #pragma unroll
    for (int cj = 0; cj < 8; ++cj) acc8[cj] = 0.f;
    #pragma unroll 16
    for (int k = 0; k < 64; ++k) {
        const float hk = h_lds[lane * 65 + k];
        #pragma unroll
        for (int cj = 0; cj < 8; ++cj)
            acc8[cj] = fmaf(hk, alpha_w[(w * 8 + cj) * 64 + k], acc8[cj]); // s_load
    }
    #pragma unroll
    for (int cj = 0; cj < 8; ++cj) {
        const int ch     = w * 8 + cj;
        const float a    = acc8[cj] + alpha_b[ch];
        const float o    = a * proj;
        const float binv = bn_g[ch] * rsqrtf(bn_v[ch] + 1e-5f);
        const float yv   = (o - bn_m[ch]) * binv + bn_b[ch];
        const float sv   = __fdividef(yv, 1.0f + __expf(-yv));   // silu
        out[((size_t)(b * 64 + ch)) * HW + (size_t)(row * 96 + col)] = sv;
    }
}

extern "C" void kernel_launch(void* const* d_in, const int* in_sizes, int n_in,
                              void* d_out, int out_size, void* d_ws, size_t ws_size,
                              hipStream_t stream) {
    const float* x   = (const float*)d_in[0];
    const float* f1w = (const float*)d_in[1];
    const float* f1b = (const float*)d_in[2];
    const float* aw  = (const float*)d_in[3];
    const float* ab  = (const float*)d_in[4];
    const float* pw  = (const float*)d_in[5];
    const float* pb  = (const float*)d_in[6];
    const float* bg  = (const float*)d_in[7];
    const float* bb  = (const float*)d_in[8];
    const float* bm  = (const float*)d_in[9];
    const float* bv  = (const float*)d_in[10];

    sac_fused<<<dim3(576), dim3(512), 0, stream>>>(
        x, f1w, f1b, aw, ab, pw, pb, bg, bb, bm, bv, (float*)d_out);
}

// Round 5
// 41.876 us; speedup vs baseline: 10.9163x; 1.0565x over previous
//
#include <hip/hip_runtime.h>

#define FLT_MAX_ 3.402823466e+38f

constexpr int PARTS = 8;             // waves per workgroup
constexpr int CB    = 4;             // channels per wave for the STATS passes (32/8)
constexpr int HW    = 9216;          // 96*96
constexpr int CHS   = 138;           // xtile per-channel stride (4*34 + 2 pad: kills lg bank conflict)
constexpr int XT    = 32 * CHS;      // 4416 floats

using bf16x8 = __attribute__((ext_vector_type(8))) short;
using f32x4  = __attribute__((ext_vector_type(4))) float;
using u32x4  = __attribute__((ext_vector_type(4))) unsigned int;

// packed bf16 pair via HW cvt (RNE): r[15:0]=bf16(a), r[31:16]=bf16(b)
__device__ inline unsigned cvtpk_bf16(float a, float b) {
    unsigned r;
    asm("v_cvt_pk_bf16_f32 %0, %1, %2" : "=v"(r) : "v"(a), "v"(b));
    return r;
}
// exact split: p = hi + lo with hi = bf16(p) (RNE); returns packed hi & lo for a pair
__device__ inline void split2(float p0, float p1, unsigned &h, unsigned &l) {
    h = cvtpk_bf16(p0, p1);
    const float h0 = __builtin_bit_cast(float, h << 16);
    const float h1 = __builtin_bit_cast(float, h & 0xFFFF0000u);
    l = cvtpk_bf16(p0 - h0, p1 - h1);
}

// ---- prep: phi_w [j=ch*9+tap][64k] fp32 -> ws fragments, K reordered j'' = tap*32+ch ----
// ws layout (uint4 units): [mat 2(hi,lo)][tap 9][n 4][lane 64], frag = 8 bf16 = 1 uint4
__global__ __launch_bounds__(256)
void prep_w(const float* __restrict__ phi_w, u32x4* __restrict__ wsq) {
    const int kb   = blockIdx.x;          // tap 0..8
    const int n    = threadIdx.x >> 6;    // 0..3
    const int lane = threadIdx.x & 63;
    const int lg   = lane >> 4, kk = lane & 15;
    float p[8];
    #pragma unroll
    for (int jj = 0; jj < 8; ++jj) {
        const int ch = lg * 8 + jj;
        p[jj] = phi_w[(ch * 9 + kb) * 64 + n * 16 + kk];
    }
    unsigned h0,h1,h2,h3, l0,l1,l2,l3;
    split2(p[0],p[1],h0,l0); split2(p[2],p[3],h1,l1);
    split2(p[4],p[5],h2,l2); split2(p[6],p[7],h3,l3);
    wsq[(kb * 4 + n) * 64 + lane]        = u32x4{h0,h1,h2,h3};
    wsq[2304 + (kb * 4 + n) * 64 + lane] = u32x4{l0,l1,l2,l3};
}

__global__ __launch_bounds__(512)
void sac_fused(const float* __restrict__ x,
               const float* __restrict__ fc1_w, const float* __restrict__ fc1_b,
               const float* __restrict__ alpha_w, const float* __restrict__ alpha_b,
               const float* __restrict__ phi_b,
               const float* __restrict__ bn_g, const float* __restrict__ bn_b,
               const float* __restrict__ bn_m, const float* __restrict__ bn_v,
               const u32x4* __restrict__ wsq,
               float* __restrict__ out)
{
    __shared__ float    xtile[XT];          // 17664 B
    __shared__ float    h_lds[64 * 65];     // 16640 B [pos][k] pad 65
    __shared__ float    red7[7 * 512];      // 14336 B {s1,mn,mx,s2,s3,s4,phib}; [0..127] reused as redP
    __shared__ unsigned cnts[16 * 64];      //  4096 B [bin][pos]
    __shared__ float    stats_lds[64 * 5];  //  1280 B
                                            // total 54016 B -> 3 WGs/CU by LDS

    const int tid  = threadIdx.x;
    const int lane = tid & 63;
    const int w    = __builtin_amdgcn_readfirstlane(tid >> 6);   // wave-uniform
    const int g    = blockIdx.x;
    const int b    = g / 144;
    const int rem  = g - b * 144;
    const int ty   = rem / 3;               // 0..47  (row pair)
    const int tx   = rem - ty * 3;          // 0..2   (32-col third)
    const int y0   = ty * 2, x0 = tx * 32;
    const int r    = lane >> 5;             // row within pair (0..1)
    const int c    = lane & 31;             // col within third (0..31)
    const int row  = y0 + r, col = x0 + c;

    cnts[tid] = 0u;
    cnts[tid + 512] = 0u;

    // ---------------- stage x tile (with halo, zero-padded) ----------------
    const float* __restrict__ xb = x + (size_t)b * 32 * HW;
    #pragma unroll
    for (int i = 0; i < 9; ++i) {
        const int idx = tid + i * 512;
        if (idx < XT) {
            const int ch   = idx / CHS;
            const int rem2 = idx - ch * CHS;
            const int rr   = rem2 / 34;          // 0..4 (4 = pad slots, never read)
            const int cc2  = rem2 - rr * 34;
            const int yg   = y0 + rr - 1;
            const int xg   = x0 + cc2 - 1;
            float v = 0.f;
            if (rr < 4 && (unsigned)yg < 96u && (unsigned)xg < 96u)
                v = xb[ch * HW + yg * 96 + xg];
            xtile[idx] = v;
        }
    }
    __syncthreads();                                 // B0

    const int xoff = (w * CB) * CHS + r * 34 + c;    // stats passes: channel-split

    // ------------- pass A: power sums s1..s4, min, max, phi_b.p -------------
    float s1 = 0.f, s2 = 0.f, s3 = 0.f, s4 = 0.f;
    float mn = FLT_MAX_, mx = -FLT_MAX_, projp = 0.f;
    #pragma unroll
    for (int cc = 0; cc < CB; ++cc)
        #pragma unroll
        for (int dy = 0; dy < 3; ++dy)
            #pragma unroll
            for (int dx = 0; dx < 3; ++dx) {
                const float p  = xtile[xoff + cc * CHS + dy * 34 + dx];
                const float pp = p * p;
                s1 += p;
                s2 = fmaf(p, p, s2);
                s3 = fmaf(pp, p, s3);
                s4 = fmaf(pp, pp, s4);
                mn = fminf(mn, p);
                mx = fmaxf(mx, p);
                const int j = (w * CB + cc) * 9 + dy * 3 + dx;   // uniform -> s_load
                projp = fmaf(p, phi_b[j], projp);
            }
    red7[tid]         = s1;
    red7[512 + tid]   = mn;
    red7[1024 + tid]  = mx;
    red7[1536 + tid]  = s2;
    red7[2048 + tid]  = s3;
    red7[2560 + tid]  = s4;
    red7[3072 + tid]  = projp;                       // phi_b . p partials
    __syncthreads();                                 // B1

    float ts1 = 0.f, tmn = FLT_MAX_, tmx = -FLT_MAX_;
    #pragma unroll
    for (int rr = 0; rr < PARTS; ++rr) {
        ts1 += red7[rr * 64 + lane];
        tmn = fminf(tmn, red7[512 + rr * 64 + lane]);
        tmx = fmaxf(tmx, red7[1024 + rr * 64 + lane]);
    }
    const float mu   = ts1 * (1.0f / 288.0f);
    const float rng  = (tmx - tmn) + 1e-6f;          // exact: min/max order-free
    const float invr = 1.0f / rng;                   // one IEEE div per position

    // ---------------- pass B: histogram only ----------------
    #pragma unroll
    for (int cc = 0; cc < CB; ++cc)
        #pragma unroll
        for (int dy = 0; dy < 3; ++dy)
            #pragma unroll
            for (int dx = 0; dx < 3; ++dx) {
                const float p  = xtile[xoff + cc * CHS + dy * 34 + dx];
                const float pn = (p - tmn) * invr;
                int bi = (int)(pn * 15.0f);
                bi = bi < 0 ? 0 : (bi > 15 ? 15 : bi);
                atomicAdd(&cnts[bi * 64 + lane], 1u);
            }
    __syncthreads();                                 // B2

    // ---------------- finalize stats (wave 0; lane = position) ----------------
    if (w == 0) {
        float u2 = 0.f, u3 = 0.f, u4 = 0.f;
        #pragma unroll
        for (int rr = 0; rr < PARTS; ++rr) {
            u2 += red7[1536 + rr * 64 + lane];
            u3 += red7[2048 + rr * 64 + lane];
            u4 += red7[2560 + rr * 64 + lane];
        }
        const float e2  = u2 * (1.0f / 288.0f);
        const float e3  = u3 * (1.0f / 288.0f);
        const float e4  = u4 * (1.0f / 288.0f);
        const float mu2 = mu * mu;
        const float var = fmaxf(e2 - mu2, 0.f);
        const float m3  = e3 - 3.f * mu * e2 + 2.f * mu * mu2;
        const float m4  = e4 - 4.f * mu * e3 + 6.f * mu2 * e2 - 3.f * mu2 * mu2;
        const float sig = sqrtf(var + 1e-6f);
        const float inv = 1.0f / (sig + 1e-6f);
        const float inv2 = inv * inv;
        const float gam = m3 * (inv2 * inv);
        const float kap = m4 * (inv2 * inv2) - 3.0f;
        float ent = 0.f;
        #pragma unroll
        for (int bi = 0; bi < 16; ++bi) {
            const float prob = (float)cnts[bi * 64 + lane] * (1.0f / 288.0f);
            ent -= prob * __logf(prob + 1e-9f);
        }
        stats_lds[lane * 5 + 0] = mu;
        stats_lds[lane * 5 + 1] = sig;
        stats_lds[lane * 5 + 2] = gam;
        stats_lds[lane * 5 + 3] = kap;
        stats_lds[lane * 5 + 4] = ent;
    }
    __syncthreads();                                 // B3

    // ---------------- h = relu(stats @ fc1_w^T + fc1_b) -> LDS ----------------
    {
        const int k = lane;
        const float wk0 = fc1_w[k * 5 + 0], wk1 = fc1_w[k * 5 + 1], wk2 = fc1_w[k * 5 + 2];
        const float wk3 = fc1_w[k * 5 + 3], wk4 = fc1_w[k * 5 + 4];
        const float bk  = fc1_b[k];
        #pragma unroll
        for (int it = 0; it < 8; ++it) {
            const int pp = (tid + it * 512) >> 6;    // wave-uniform position
            float acc = bk;
            acc = fmaf(stats_lds[pp * 5 + 0], wk0, acc);
            acc = fmaf(stats_lds[pp * 5 + 1], wk1, acc);
            acc = fmaf(stats_lds[pp * 5 + 2], wk2, acc);
            acc = fmaf(stats_lds[pp * 5 + 3], wk3, acc);
            acc = fmaf(stats_lds[pp * 5 + 4], wk4, acc);
            h_lds[pp * 65 + k] = fmaxf(acc, 0.f);
        }
    }
    __syncthreads();                                 // B4

    // ======== t-GEMM via MFMA: T[64 pos][64 k] = P[64x288] . W[288x64] ========
    // K permuted as j'' = tap*32 + ch (A & B identically). Wave w: m = w>>1, n = (w&1)*2 + {0,1}.
    // bf16 triple-split: T = (Ph+Pl).(Wh+Wl), all 4 products, fp32 accum -> ~2^-15 rel.
    {
        const int m    = w >> 1;
        const int np   = (w & 1) * 2;
        const int lg   = lane >> 4;
        const int posa = m * 16 + (lane & 15);
        const int ra   = posa >> 5, ca = posa & 31;
        const int abase = lg * 8 * CHS + ra * 34 + ca;   // + jj*CHS + dy*34 + dx (imm)

        f32x4 acc0 = {0.f, 0.f, 0.f, 0.f};
        f32x4 acc1 = {0.f, 0.f, 0.f, 0.f};

        #pragma unroll
        for (int tap = 0; tap < 9; ++tap) {
            const int dy = tap / 3, dx = tap % 3;        // compile-time
            const u32x4 bh0 = wsq[(tap * 4 + np) * 64 + lane];
            const u32x4 bh1 = wsq[(tap * 4 + np + 1) * 64 + lane];
            const u32x4 bl0 = wsq[2304 + (tap * 4 + np) * 64 + lane];
            const u32x4 bl1 = wsq[2304 + (tap * 4 + np + 1) * 64 + lane];

            const int ab = abase + dy * 34 + dx;
            const float p0 = xtile[ab + 0 * CHS], p1 = xtile[ab + 1 * CHS];
            const float p2 = xtile[ab + 2 * CHS], p3 = xtile[ab + 3 * CHS];
            const float p4 = xtile[ab + 4 * CHS], p5 = xtile[ab + 5 * CHS];
            const float p6 = xtile[ab + 6 * CHS], p7 = xtile[ab + 7 * CHS];
            unsigned ah0,ah1,ah2,ah3, al0,al1,al2,al3;
            split2(p0,p1,ah0,al0); split2(p2,p3,ah1,al1);
            split2(p4,p5,ah2,al2); split2(p6,p7,ah3,al3);
            const bf16x8 Ah = __builtin_bit_cast(bf16x8, u32x4{ah0,ah1,ah2,ah3});
            const bf16x8 Al = __builtin_bit_cast(bf16x8, u32x4{al0,al1,al2,al3});
            const bf16x8 Bh0 = __builtin_bit_cast(bf16x8, bh0);
            const bf16x8 Bl0 = __builtin_bit_cast(bf16x8, bl0);
            const bf16x8 Bh1 = __builtin_bit_cast(bf16x8, bh1);
            const bf16x8 Bl1 = __builtin_bit_cast(bf16x8, bl1);

            acc0 = __builtin_amdgcn_mfma_f32_16x16x32_bf16(Ah, Bh0, acc0, 0, 0, 0);
            acc0 = __builtin_amdgcn_mfma_f32_16x16x32_bf16(Ah, Bl0, acc0, 0, 0, 0);
            acc0 = __builtin_amdgcn_mfma_f32_16x16x32_bf16(Al, Bh0, acc0, 0, 0, 0);
            acc0 = __builtin_amdgcn_mfma_f32_16x16x32_bf16(Al, Bl0, acc0, 0, 0, 0);
            acc1 = __builtin_amdgcn_mfma_f32_16x16x32_bf16(Ah, Bh1, acc1, 0, 0, 0);
            acc1 = __builtin_amdgcn_mfma_f32_16x16x32_bf16(Ah, Bl1, acc1, 0, 0, 0);
            acc1 = __builtin_amdgcn_mfma_f32_16x16x32_bf16(Al, Bh1, acc1, 0, 0, 0);
            acc1 = __builtin_amdgcn_mfma_f32_16x16x32_bf16(Al, Bl1, acc1, 0, 0, 0);
        }

        // proj partials: C/D layout col = lane&15 (k), row = lg*4 + q (pos)
        const int k0 = np * 16 + (lane & 15);
        const int k1 = k0 + 16;
        float pr0, pr1, pr2, pr3;
        {
            const int pb = (m * 16 + lg * 4) * 65;
            pr0 = acc0[0] * h_lds[pb + 0 * 65 + k0] + acc1[0] * h_lds[pb + 0 * 65 + k1];
            pr1 = acc0[1] * h_lds[pb + 1 * 65 + k0] + acc1[1] * h_lds[pb + 1 * 65 + k1];
            pr2 = acc0[2] * h_lds[pb + 2 * 65 + k0] + acc1[2] * h_lds[pb + 2 * 65 + k1];
            pr3 = acc0[3] * h_lds[pb + 3 * 65 + k0] + acc1[3] * h_lds[pb + 3 * 65 + k1];
        }
        #pragma unroll
        for (int msk = 1; msk < 16; msk <<= 1) {
            pr0 += __shfl_xor(pr0, msk);
            pr1 += __shfl_xor(pr1, msk);
            pr2 += __shfl_xor(pr2, msk);
            pr3 += __shfl_xor(pr3, msk);
        }
        if ((lane & 15) == 0) {                      // redP aliases red7[0..127] (dead)
            const int pb = m * 16 + lg * 4;
            red7[(pb + 0) * 2 + (w & 1)] = pr0;
            red7[(pb + 1) * 2 + (w & 1)] = pr1;
            red7[(pb + 2) * 2 + (w & 1)] = pr2;
            red7[(pb + 3) * 2 + (w & 1)] = pr3;
        }
    }
    __syncthreads();                                 // B5

    float proj = red7[2 * lane] + red7[2 * lane + 1];
    #pragma unroll
    for (int rr = 0; rr < PARTS; ++rr)
        proj += red7[3072 + rr * 64 + lane];         // phi_b . p

    // ---------------- alpha (8 channels per wave) + BN + SiLU ----------------
    float acc8[8];
    #pragma unroll
    for (int cj = 0; cj < 8; ++cj) acc8[cj] = 0.f;
    #pragma unroll 16
    for (int k = 0; k < 64; ++k) {
        const float hk = h_lds[lane * 65 + k];
        #pragma unroll
        for (int cj = 0; cj < 8; ++cj)
            acc8[cj] = fmaf(hk, alpha_w[(w * 8 + cj) * 64 + k], acc8[cj]); // s_load
    }
    #pragma unroll
    for (int cj = 0; cj < 8; ++cj) {
        const int ch     = w * 8 + cj;
        const float a    = acc8[cj] + alpha_b[ch];
        const float o    = a * proj;
        const float binv = bn_g[ch] * rsqrtf(bn_v[ch] + 1e-5f);
        const float yv   = (o - bn_m[ch]) * binv + bn_b[ch];
        const float sv   = __fdividef(yv, 1.0f + __expf(-yv));   // silu
        out[((size_t)(b * 64 + ch)) * HW + (size_t)(row * 96 + col)] = sv;
    }
}

extern "C" void kernel_launch(void* const* d_in, const int* in_sizes, int n_in,
                              void* d_out, int out_size, void* d_ws, size_t ws_size,
                              hipStream_t stream) {
    const float* x   = (const float*)d_in[0];
    const float* f1w = (const float*)d_in[1];
    const float* f1b = (const float*)d_in[2];
    const float* aw  = (const float*)d_in[3];
    const float* ab  = (const float*)d_in[4];
    const float* pw  = (const float*)d_in[5];
    const float* pb  = (const float*)d_in[6];
    const float* bg  = (const float*)d_in[7];
    const float* bb  = (const float*)d_in[8];
    const float* bm  = (const float*)d_in[9];
    const float* bv  = (const float*)d_in[10];

    u32x4* wsq = (u32x4*)d_ws;   // 73728 B used

    prep_w<<<dim3(9), dim3(256), 0, stream>>>(pw, wsq);
    sac_fused<<<dim3(576), dim3(512), 0, stream>>>(
        x, f1w, f1b, aw, ab, pb, bg, bb, bm, bv, wsq, (float*)d_out);
}